// Round 24
// baseline (1220.860 us; speedup 1.0000x reference)
//
#include <hip/hip_runtime.h>
#include <hip/hip_bf16.h>
#include <math.h>

// Problem constants (from reference)
#define BB 64
#define TT 2048
#define VV 4096
#define EE 128
#define H2 128
#define SS 8
#define CC 2

#define L2E  1.44269504f      // log2(e)
#define L2E2 2.88539008f      // 2*log2(e)

typedef _Float16 h2f __attribute__((ext_vector_type(2)));

// v_rcp_f32 instead of precise IEEE divide — round-19 verified win (-10%).
__device__ __forceinline__ float fast_rcp(float x) {
#if __has_builtin(__builtin_amdgcn_rcpf)
    return __builtin_amdgcn_rcpf(x);
#else
    return 1.f / x;
#endif
}

__device__ __forceinline__ float exp2_fast(float x) {
#if __has_builtin(__builtin_amdgcn_exp2f)
    return __builtin_amdgcn_exp2f(x);
#else
    return __exp2f(x);
#endif
}

// Preacts pre-scaled by log2e (i,f,o) / 2*log2e (g) via weights + EG table.
__device__ __forceinline__ float sig2(float y) {          // y = x*log2e
    return fast_rcp(1.f + exp2_fast(-y));
}
__device__ __forceinline__ float tanh2(float y) {         // y = x*2*log2e
    return fmaf(-2.f, fast_rcp(exp2_fast(y) + 1.f), 1.f);
}

__device__ __forceinline__ float dot2acc(h2f w, h2f h, float acc) {
#if __has_builtin(__builtin_amdgcn_fdot2)
    return __builtin_amdgcn_fdot2(w, h, acc, false);
#else
    return fmaf((float)w.x, (float)h.x, fmaf((float)w.y, (float)h.y, acc));
#endif
}

// lane^1 swap as pure-VALU DPP (quad_perm [1,0,3,2] = ctrl 0xB1).
__device__ __forceinline__ float xor1_swap(float x) {
#if __has_builtin(__builtin_amdgcn_update_dpp)
    return __builtin_bit_cast(float,
        __builtin_amdgcn_update_dpp(0, __builtin_bit_cast(int, x),
                                    0xB1, 0xF, 0xF, true));
#else
    return __shfl_xor(x, 1, 64);
#endif
}

// LDS-only barrier (no vmcnt drain — keeps EG prefetch in flight).
__device__ __forceinline__ void lds_barrier() {
    asm volatile("s_waitcnt lgkmcnt(0)" ::: "memory");
    __builtin_amdgcn_s_barrier();
    asm volatile("" ::: "memory");
}

// ---------------------------------------------------------------------------
// Kernel 1: EG gate-bias table, PAIR layout, PRE-SCALED by log2e / 2*log2e.
// ---------------------------------------------------------------------------
__global__ __launch_bounds__(256) void eg_gemm(
    const float* __restrict__ emb,
    const float* __restrict__ Wf, const float* __restrict__ bf,
    const float* __restrict__ Wb, const float* __restrict__ bb,
    float* __restrict__ EGp)
{
    __shared__ float As[64][68];
    __shared__ float Bs[64][68];

    const int tid = threadIdx.x;
    const int tx = tid & 15, ty = tid >> 4;
    const int m0 = blockIdx.y * 64;
    const int n0 = blockIdx.x * 64;

    const float* Bsrc;
    const float* bias;
    if (n0 < 512) { Bsrc = Wf + n0 * EE; bias = bf + n0; }
    else          { Bsrc = Wb + (n0 - 512) * EE; bias = bb + (n0 - 512); }

    float acc[4][4] = {};

    for (int kc = 0; kc < 2; ++kc) {
        for (int c = tid; c < 1024; c += 256) {
            int r = c >> 4, q = c & 15;
            float4 av = *(const float4*)(emb + (size_t)(m0 + r) * EE + kc * 64 + q * 4);
            As[q * 4 + 0][r] = av.x; As[q * 4 + 1][r] = av.y;
            As[q * 4 + 2][r] = av.z; As[q * 4 + 3][r] = av.w;
            float4 bv = *(const float4*)(Bsrc + (size_t)r * EE + kc * 64 + q * 4);
            Bs[q * 4 + 0][r] = bv.x; Bs[q * 4 + 1][r] = bv.y;
            Bs[q * 4 + 2][r] = bv.z; Bs[q * 4 + 3][r] = bv.w;
        }
        __syncthreads();
        #pragma unroll 8
        for (int k = 0; k < 64; ++k) {
            float4 a4 = *(const float4*)&As[k][4 * ty];
            float4 b4 = *(const float4*)&Bs[k][4 * tx];
            float a[4] = {a4.x, a4.y, a4.z, a4.w};
            float b[4] = {b4.x, b4.y, b4.z, b4.w};
            #pragma unroll
            for (int i = 0; i < 4; ++i)
                #pragma unroll
                for (int jn = 0; jn < 4; ++jn)
                    acc[i][jn] = fmaf(a[i], b[jn], acc[i][jn]);
        }
        __syncthreads();
    }

    #pragma unroll
    for (int i = 0; i < 4; ++i) {
        int m = m0 + 4 * ty + i;                 // vocab index v
        #pragma unroll
        for (int jn = 0; jn < 4; ++jn) {
            int nn = 4 * tx + jn;
            int n = n0 + nn;                     // combined gate col
            int d = n >> 9;
            int r = n & 511;
            int slot = (r >> 7) & 1;
            int p = (r & 127) + (r >= 256 ? 128 : 0);
            float scale = ((r >> 7) == 2) ? L2E2 : L2E;   // gate g: 2*log2e
            EGp[(((size_t)m * 2 + d) * 256 + p) * 2 + slot] =
                (acc[i][jn] + bias[nn]) * scale;
        }
    }
}

// ---------------------------------------------------------------------------
// Kernel 2: fused LSTM recurrence + ragged segment max-pool.
// Base = round-23 (1126 us lstm_rec): 128 blocks (b,dir), 4 waves,
// 1 wave/SIMD; k-split (8 b128 reads/lane); DPP gate exchange; exp2-native
// activations (log2e pre-folded); distance-2 EG prefetch; LDS-only barrier;
// publish-first.
//
// Round-24 (this): last identified serial-chain cycles:
//  1. L2E2 folded into tg ON THE GATE CHAIN (odd lane: t_own=tanh2*L2E2);
//     even lane's cell then tracks c' = c*2log2e exactly, so hn uses
//     tanh2(c') with NO mul — removes one v_mul from the longest serial
//     segment (post-c-update chain).
//  2. EG reload moved AFTER the h publish — fully off the critical chain
//     (cover still >> HBM miss latency).
// Pre-commitment: <2% gain => declare structural floor next round.
// ---------------------------------------------------------------------------

#define LSTM_STEP(T_, BUF_, XV_, TOKN_, ISSUE_)                              \
  {                                                                          \
    float2 xv_ = (XV_);          /* capture BEFORE in-place reload */        \
    float c0a = 0.f, c1a = 0.f, c2a = 0.f, c3a = 0.f;                        \
    float c0b = 0.f, c1b = 0.f, c2b = 0.f, c3b = 0.f;                        \
    const int4* hb4 = (const int4*)&hpk[BUF_][hoff];                         \
    _Pragma("unroll")                                                        \
    for (int k8 = 0; k8 < 8; k8 += 2) {                                      \
      int4 u0 = hb4[k8];                                                     \
      int4 u1 = hb4[k8 + 1];                                                 \
      h2f h0 = __builtin_bit_cast(h2f, u0.x);                                \
      h2f h1 = __builtin_bit_cast(h2f, u0.y);                                \
      h2f h2 = __builtin_bit_cast(h2f, u0.z);                                \
      h2f h3 = __builtin_bit_cast(h2f, u0.w);                                \
      h2f h4 = __builtin_bit_cast(h2f, u1.x);                                \
      h2f h5 = __builtin_bit_cast(h2f, u1.y);                                \
      h2f h6 = __builtin_bit_cast(h2f, u1.z);                                \
      h2f h7 = __builtin_bit_cast(h2f, u1.w);                                \
      c0a = dot2acc(wg[0][4 * k8 + 0], h0, c0a);                             \
      c1a = dot2acc(wg[1][4 * k8 + 0], h0, c1a);                             \
      c2a = dot2acc(wg[2][4 * k8 + 0], h0, c2a);                             \
      c3a = dot2acc(wg[3][4 * k8 + 0], h0, c3a);                             \
      c0b = dot2acc(wg[0][4 * k8 + 4], h4, c0b);                             \
      c1b = dot2acc(wg[1][4 * k8 + 4], h4, c1b);                             \
      c2b = dot2acc(wg[2][4 * k8 + 4], h4, c2b);                             \
      c3b = dot2acc(wg[3][4 * k8 + 4], h4, c3b);                             \
      c0a = dot2acc(wg[0][4 * k8 + 1], h1, c0a);                             \
      c1a = dot2acc(wg[1][4 * k8 + 1], h1, c1a);                             \
      c2a = dot2acc(wg[2][4 * k8 + 1], h1, c2a);                             \
      c3a = dot2acc(wg[3][4 * k8 + 1], h1, c3a);                             \
      c0b = dot2acc(wg[0][4 * k8 + 5], h5, c0b);                             \
      c1b = dot2acc(wg[1][4 * k8 + 5], h5, c1b);                             \
      c2b = dot2acc(wg[2][4 * k8 + 5], h5, c2b);                             \
      c3b = dot2acc(wg[3][4 * k8 + 5], h5, c3b);                             \
      c0a = dot2acc(wg[0][4 * k8 + 2], h2, c0a);                             \
      c1a = dot2acc(wg[1][4 * k8 + 2], h2, c1a);                             \
      c2a = dot2acc(wg[2][4 * k8 + 2], h2, c2a);                             \
      c3a = dot2acc(wg[3][4 * k8 + 2], h2, c3a);                             \
      c0b = dot2acc(wg[0][4 * k8 + 6], h6, c0b);                             \
      c1b = dot2acc(wg[1][4 * k8 + 6], h6, c1b);                             \
      c2b = dot2acc(wg[2][4 * k8 + 6], h6, c2b);                             \
      c3b = dot2acc(wg[3][4 * k8 + 6], h6, c3b);                             \
      c0a = dot2acc(wg[0][4 * k8 + 3], h3, c0a);                             \
      c1a = dot2acc(wg[1][4 * k8 + 3], h3, c1a);                             \
      c2a = dot2acc(wg[2][4 * k8 + 3], h3, c2a);                             \
      c3a = dot2acc(wg[3][4 * k8 + 3], h3, c3a);                             \
      c0b = dot2acc(wg[0][4 * k8 + 7], h7, c0b);                             \
      c1b = dot2acc(wg[1][4 * k8 + 7], h7, c1b);                             \
      c2b = dot2acc(wg[2][4 * k8 + 7], h7, c2b);                             \
      c3b = dot2acc(wg[3][4 * k8 + 7], h7, c3b);                             \
    }                                                                        \
    float o0 = c0a + c0b;   /* partial i-preact (own k-half, scaled) */      \
    float o1 = c1a + c1b;   /* partial f-preact */                           \
    float o2 = c2a + c2b;   /* partial g-preact (scaled 2*log2e) */          \
    float o3 = c3a + c3b;   /* partial o-preact */                           \
    float x0 = xor1_swap(o0);                                                \
    float x1 = xor1_swap(o1);                                                \
    float x2 = xor1_swap(o2);                                                \
    float x3 = xor1_swap(o3);                                                \
    float g0 = (evn ? (o0 + x0) : (o2 + x2)) + xv_.x;  /* i | g preact */    \
    float g1 = (evn ? (o1 + x1) : (o3 + x3)) + xv_.y;  /* f | o preact */    \
    float s_own = sig2(g1);                            /* sf | so */         \
    /* odd lane pre-scales tg by 2log2e -> even cell tracks c*2log2e */      \
    float t_own = evn ? sig2(g0) : (tanh2(g0) * L2E2);  /* si | tg*L2E2 */   \
    float t_x = xor1_swap(t_own);                                            \
    float s_x = xor1_swap(s_own);                                            \
    c = s_own * c + t_own * t_x;       /* even: c' = 2log2e * cell */        \
    float hn = s_x * tanh2(c);         /* no mul before exp2 */              \
    /* publish FIRST: write drains while pooling bookkeeping runs */         \
    if (evn) ((_Float16*)hpk[(BUF_) ^ 1])[u] = (_Float16)hn;                 \
    /* EG gather for T_+2 — fully off the serial chain now */                \
    if (ISSUE_) {                                                            \
      (XV_) = egp[((size_t)(TOKN_) * 2 + dir) * 256 + p];                    \
      int i4_ = dir ? (L - 5 - (T_)) : ((T_) + 4);          /* tok T_+4 */   \
      i4_ = max(0, min(TT - 1, i4_));                                        \
      (TOKN_) = srow[i4_];                                                   \
    }                                                                        \
    const int tt_ = dir ? (L - 1 - (T_)) : (T_);                             \
    bool bnd_ = dir ? (tt_ < nb) : (tt_ >= nb);                              \
    if (bnd_) {                                                              \
      if (evn) {                                                             \
        float v = pm;                                                        \
        if (haspad && cur_seg >= padlo) v = fmaxf(v, 0.f);                   \
        pws[(((size_t)b * 2 + dir) * SS + cur_seg) * H2 + u] = v;            \
      }                                                                      \
      pm = -INFINITY;                                                        \
      cur_seg += dir ? -1 : 1;                                               \
      nb += dir ? -wseg : wseg;                                              \
    }                                                                        \
    pm = fmaxf(pm, hn);                                                      \
    lds_barrier();                                                           \
  }

__global__ __launch_bounds__(256, 1) void lstm_rec(
    const int* __restrict__ sentence, const int* __restrict__ lens,
    const float* __restrict__ Whhf, const float* __restrict__ Whhb,
    const float* __restrict__ EGp, float* __restrict__ pws)
{
    const int bid = blockIdx.x;
    const int b = bid >> 1;
    const int dir = bid & 1;            // 0 = forward, 1 = backward
    const int tid = threadIdx.x;
    const int l = tid & 63;             // lane in wave
    const int wv = tid >> 6;            // wave 0..3
    const int u = wv * 32 + (l >> 1);   // hidden unit this lane pair covers
    const bool evn = (l & 1) == 0;      // even lane: (i,f) + cell state
    const int L = lens[b];
    const int* __restrict__ srow = sentence + (size_t)b * TT;
    const float* __restrict__ Wh = (dir == 0 ? Whhf : Whhb);

    // k-half this lane covers: even k in [0,64), odd k in [64,128)
    const int kb = evn ? 0 : 64;
    const int hoff = evn ? 0 : 32;      // int offset into hpk row (64 f16 = 32 ints)

    // --- W_hh: ALL 4 gate rows of unit u, own k-half, PRE-SCALED. ---
    h2f wg[4][32];
    #pragma unroll
    for (int g = 0; g < 4; ++g) {
        const float wsc = (g == 2) ? L2E2 : L2E;
        const float* src = Wh + (size_t)(g * 128 + u) * H2 + kb;
        #pragma unroll
        for (int k4 = 0; k4 < 16; ++k4) {
            float4 a = *(const float4*)(src + 4 * k4);
            wg[g][2 * k4 + 0].x = (_Float16)(a.x * wsc);
            wg[g][2 * k4 + 0].y = (_Float16)(a.y * wsc);
            wg[g][2 * k4 + 1].x = (_Float16)(a.z * wsc);
            wg[g][2 * k4 + 1].y = (_Float16)(a.w * wsc);
        }
    }

    __shared__ __align__(16) int hpk[2][64];   // double-buffered packed f16 h pairs
    if (tid < 64) hpk[0][tid] = 0;

    // per-lane EG pair column (even: (i,f) of u ; odd: (g,o) of u)
    const int p = evn ? u : (128 + u);
    const float2* __restrict__ egp = (const float2*)EGp;

    float c = 0.f;
    float pm = -INFINITY;

    const int wseg = (L + SS - 1) >> 3;
    const bool haspad = (SS * wseg > L);
    const int padlo = L / wseg;
    int cur_seg = dir ? (SS - 1) : 0;
    int nb = dir ? (SS - 1) * wseg : wseg;

    // --- prefetch pipeline: EG pairs for t=0,1 in flight; tokens for t=2,3 staged ---
    float2 e0, e1;
    int tokA, tokB;
    {
        int j0 = dir ? (L - 1) : 0;
        e0 = egp[((size_t)srow[j0] * 2 + dir) * 256 + p];
        int j1 = dir ? (L - 2) : 1;  j1 = max(0, min(TT - 1, j1));
        e1 = egp[((size_t)srow[j1] * 2 + dir) * 256 + p];
        int j2 = dir ? (L - 3) : 2;  j2 = max(0, min(TT - 1, j2));
        tokA = srow[j2];
        int j3 = dir ? (L - 4) : 3;  j3 = max(0, min(TT - 1, j3));
        tokB = srow[j3];
    }

    __syncthreads();                    // hpk[0] init visible (full drain ok here)

    int t = 0;
    for (; t + 2 <= L; t += 2) {
        LSTM_STEP(t,     0, e0, tokA, true);
        LSTM_STEP(t + 1, 1, e1, tokB, true);
    }
    if (t < L) {                        // odd-L tail (t even -> buf 0)
        LSTM_STEP(t, 0, e0, tokA, false);
    }

    if (evn) {
        float v = pm;
        if (haspad && cur_seg >= padlo) v = fmaxf(v, 0.f);
        pws[(((size_t)b * 2 + dir) * SS + cur_seg) * H2 + u] = v;
    }
}

// ---------------------------------------------------------------------------
// Kernel 3: out[b,c] = b_dense[c] + sum_k flat[b,k] * W_dense[c,k]
// ---------------------------------------------------------------------------
__global__ __launch_bounds__(256) void dense_k(
    const float* __restrict__ pws, const float* __restrict__ Wd,
    const float* __restrict__ bd, float* __restrict__ out)
{
    const int b = blockIdx.x;
    const int tid = threadIdx.x;
    float a0 = 0.f, a1 = 0.f;
    for (int k = tid; k < 2048; k += 256) {
        int h = k >> 3, s = k & 7;
        int dir = h >> 7, j = h & 127;
        float v = pws[(((size_t)b * 2 + dir) * SS + s) * H2 + j];
        a0 = fmaf(v, Wd[k], a0);
        a1 = fmaf(v, Wd[2048 + k], a1);
    }
    __shared__ float r0[256], r1[256];
    r0[tid] = a0; r1[tid] = a1;
    __syncthreads();
    for (int s = 128; s > 0; s >>= 1) {
        if (tid < s) { r0[tid] += r0[tid + s]; r1[tid] += r1[tid + s]; }
        __syncthreads();
    }
    if (tid == 0) {
        out[b * 2 + 0] = r0[0] + bd[0];
        out[b * 2 + 1] = r1[0] + bd[1];
    }
}

// ---------------------------------------------------------------------------
extern "C" void kernel_launch(void* const* d_in, const int* in_sizes, int n_in,
                              void* d_out, int out_size, void* d_ws, size_t ws_size,
                              hipStream_t stream)
{
    const int*   sentence = (const int*)d_in[0];
    const int*   lens     = (const int*)d_in[1];
    const float* emb      = (const float*)d_in[2];
    const float* Wihf     = (const float*)d_in[3];
    const float* Whhf     = (const float*)d_in[4];
    const float* bf       = (const float*)d_in[5];
    const float* Wihb     = (const float*)d_in[6];
    const float* Whhb     = (const float*)d_in[7];
    const float* bb       = (const float*)d_in[8];
    const float* Wd       = (const float*)d_in[9];
    const float* bd       = (const float*)d_in[10];
    float* out = (float*)d_out;

    float* EGp = (float*)d_ws;                    // [4096][2][256][2] fp32 = 16 MB
    float* pws = EGp + (size_t)VV * 1024;         // [64][2][8][128] fp32 = 512 KB

    eg_gemm<<<dim3(16, 64), 256, 0, stream>>>(emb, Wihf, bf, Wihb, bb, EGp);
    lstm_rec<<<128, 256, 0, stream>>>(sentence, lens, Whhf, Whhb, EGp, pws);
    dense_k<<<64, 256, 0, stream>>>(pws, Wd, bd, out);
}